// Round 9
// baseline (268.093 us; speedup 1.0000x reference)
//
#include <hip/hip_runtime.h>

#define Bdim 256
#define Tdim 512
#define Kdim 128
#define NT   128   // 2 waves; lane (j = tid>>2, g = tid&3): col tid, rows [32g,32g+32)
#define CHUNK 8

typedef float v2f __attribute__((ext_vector_type(2)));

// Raw barrier: drain LDS ops only (NOT vmcnt) so global prefetches stay in
// flight across steps; then s_barrier. "memory" stops compiler reordering.
#define BAR() asm volatile("s_waitcnt lgkmcnt(0)\n\ts_barrier" ::: "memory")

// Quad-lane butterfly add via DPP. 0xB1 = quad_perm [1,0,3,2] (xor 1);
// 0x4E = [2,3,0,1] (xor 2). Control must be a constant -> template param.
template <int CTRL>
__device__ __forceinline__ float dpp_add(float v) {
    int r = __builtin_amdgcn_update_dpp(0, __float_as_int(v), CTRL, 0xF, 0xF, true);
    return v + __int_as_float(r);
}

// One block per batch element, 128 threads (2 waves — the minimum that spans
// K=128 with a register-feasible E-fragment; fewer waves = less barrier skew,
// measured slope ~25cy/wave across r3/r8/r6).
// Lane (j,g) owns output column tid (= 4j+g) and rows [32g, 32g+32):
// E-fragment 32 rows x 4 cols = 64 v2f = 128 VGPRs. Register residency forced
// r7-style: __launch_bounds__ with NO second arg + amdgpu_waves_per_eu(1,1)
// (r8 showed launch_bounds(N,1) + the attribute reverts to 60 VGPRs).
// Per step: 8 ds_read_b128 (rotated by j), 64 v_pk_fma_f32, quad-only DPP
// reduce (8 adds + 2 selects — the 4 row-groups of a column quad are
// CONSECUTIVE lanes), every lane writes its own column (no mask), lgkm-only
// 2-wave barrier. alpha in LINEAR space; renorm by A[0] every 4th step.
__global__ __launch_bounds__(NT) __attribute__((amdgpu_waves_per_eu(1, 1)))
void crf_nll_kernel(
    const float* __restrict__ logits,   // B*T*K fp32
    const int*   __restrict__ labels,   // B*T   int32
    const int*   __restrict__ seq_lens, // B     int32
    const float* __restrict__ trans,    // K*K   fp32
    float* __restrict__ out)            // 1     fp32 (pre-zeroed)
{
    const int b   = blockIdx.x;
    const int tid = threadIdx.x;        // == this lane's column
    const int j   = tid >> 2;           // column quad 0..31
    const int g   = tid & 3;            // row slice [32g, 32g+32)
    const int L   = seq_lens[b];        // 1..T (uniform per block)

    __shared__ float pbuf[2][Kdim];
    __shared__ float red2[NT / 64];

    const int*   lab_b   = labels + (size_t)b * Tdim;
    const float* logit_b = logits + (size_t)b * Tdim * Kdim;

    // ---- E fragment: rows 4*f4(ii)..+3, cols 4j..4j+3, where
    // f4(ii) = 8g + ((ii+j)&7). The j-rotation spreads each read
    // instruction's addresses over all 32 float4 slots of the A vector.
    v2f e01[8][4], e23[8][4];
    #pragma unroll
    for (int ii = 0; ii < 8; ++ii) {
        const int f4 = (g << 3) + ((ii + j) & 7);
        #pragma unroll
        for (int ci = 0; ci < 4; ++ci) {
            const float4 tr =
                *(const float4*)&trans[(size_t)(4 * f4 + ci) * Kdim + 4 * j];
            e01[ii][ci] = (v2f){__expf(tr.x), __expf(tr.y)};
            e23[ii][ci] = (v2f){__expf(tr.z), __expf(tr.w)};
        }
    }

    // ---- gold-path score: 4 timesteps per thread ----
    float s = 0.f;
    #pragma unroll
    for (int t0 = 0; t0 < Tdim; t0 += NT) {
        const int t = t0 + tid;
        if (t < L) {
            const int lb = lab_b[t];
            s += logit_b[(size_t)t * Kdim + lb];
            if (t >= 1) s += trans[(size_t)lab_b[t - 1] * Kdim + lb];
        }
    }
    #pragma unroll
    for (int o = 32; o > 0; o >>= 1) s += __shfl_down(s, o, 64);
    if ((tid & 63) == 0) red2[tid >> 6] = s;

    // ---- init alpha (t = 0), linear space; every lane owns a column ----
    pbuf[0][tid] = __expf(logit_b[tid]);
    float off = 0.f;
    int cb = 0;
    __syncthreads();
    const float score = red2[0] + red2[1];  // uniform

    // ---- prefetch first logit chunk (t = 1..8), this lane's column ----
    float curl[CHUNK], nxtl[CHUNK], ex[CHUNK];
    #pragma unroll
    for (int u = 0; u < CHUNK; ++u) {
        const int tt = 1 + u;
        curl[u] = (tt < Tdim) ? logit_b[(size_t)tt * Kdim + tid] : 0.f;
    }

    // One forward step. RENORM steps divide by A[0] (uniform) and bank the
    // log into off; growth between renorms <= ~e^44 << fp32 max.
#define STEP_BODY(SC_EXPR, RENORM)                                          \
    do {                                                                    \
        const float4* a4 = (const float4*)pbuf[cb];                         \
        float p0 = 1.f;                                                     \
        if (RENORM) p0 = pbuf[cb][0];                                       \
        v2f A0 = {0.f, 0.f}, A1 = {0.f, 0.f};                               \
        v2f B0 = {0.f, 0.f}, B1 = {0.f, 0.f};                               \
        _Pragma("unroll")                                                   \
        for (int ii = 0; ii < 8; ++ii) {                                    \
            const float4 p = a4[(g << 3) + ((ii + j) & 7)];                 \
            A0 = __builtin_elementwise_fma((v2f){p.x, p.x}, e01[ii][0], A0);\
            A1 = __builtin_elementwise_fma((v2f){p.x, p.x}, e23[ii][0], A1);\
            B0 = __builtin_elementwise_fma((v2f){p.y, p.y}, e01[ii][1], B0);\
            B1 = __builtin_elementwise_fma((v2f){p.y, p.y}, e23[ii][1], B1);\
            A0 = __builtin_elementwise_fma((v2f){p.z, p.z}, e01[ii][2], A0);\
            A1 = __builtin_elementwise_fma((v2f){p.z, p.z}, e23[ii][2], A1);\
            B0 = __builtin_elementwise_fma((v2f){p.w, p.w}, e01[ii][3], B0);\
            B1 = __builtin_elementwise_fma((v2f){p.w, p.w}, e23[ii][3], B1);\
        }                                                                   \
        const v2f s01 = A0 + B0;   /* partials, cols 4j+0 / 4j+1 */         \
        const v2f s23 = A1 + B1;   /* partials, cols 4j+2 / 4j+3 */         \
        float c0 = s01.x, c1 = s01.y, c2 = s23.x, c3 = s23.y;               \
        c0 = dpp_add<0xB1>(c0); c0 = dpp_add<0x4E>(c0);                     \
        c1 = dpp_add<0xB1>(c1); c1 = dpp_add<0x4E>(c1);                     \
        c2 = dpp_add<0xB1>(c2); c2 = dpp_add<0x4E>(c2);                     \
        c3 = dpp_add<0xB1>(c3); c3 = dpp_add<0x4E>(c3);                     \
        float sel  = (g & 1) ? c1 : c0;                                     \
        float selh = (g & 1) ? c3 : c2;                                     \
        sel = (g & 2) ? selh : sel;                                         \
        float anew = sel * (SC_EXPR);                                       \
        if (RENORM) {                                                       \
            const float lp0 = __logf(p0);                                   \
            anew *= __expf(-lp0);                                           \
            off  += lp0;                                                    \
        }                                                                   \
        pbuf[cb ^ 1][tid] = anew;                                           \
        cb ^= 1;                                                            \
        BAR();                                                              \
    } while (0)

    // ---- forward recursion: branchless full chunks, then a short tail ----
    int tb = 1;
    for (; tb + CHUNK <= L; tb += CHUNK) {
        #pragma unroll
        for (int u = 0; u < CHUNK; ++u) {    // prefetch next chunk
            const int tt = tb + CHUNK + u;
            nxtl[u] = (tt < Tdim) ? logit_b[(size_t)tt * Kdim + tid] : 0.f;
        }
        #pragma unroll
        for (int u = 0; u < CHUNK; ++u)      // exp(logit) off the serial path
            ex[u] = __expf(curl[u]);
        #pragma unroll
        for (int u = 0; u < CHUNK; ++u)      // no per-step t<L check
            STEP_BODY(ex[u], (u & 3) == 3);
        #pragma unroll
        for (int u = 0; u < CHUNK; ++u) curl[u] = nxtl[u];
    }
    // tail: < CHUNK remaining steps; curl[] already holds t = tb..tb+7
    for (int u = 0; tb + u < L; ++u)
        STEP_BODY(__expf(curl[u]), (u & 3) == 3);

#undef STEP_BODY

    // ---- log_z = off + log(sum_j A[j]); nll = log_z - score ----
    __syncthreads();
    float as = pbuf[cb][tid];
    #pragma unroll
    for (int o = 32; o > 0; o >>= 1) as += __shfl_down(as, o, 64);
    __syncthreads();
    if ((tid & 63) == 0) red2[tid >> 6] = as;
    __syncthreads();
    if (tid == 0) {
        const float logz = off + __logf(red2[0] + red2[1]);
        atomicAdd(out, logz - score);
    }
}

extern "C" void kernel_launch(void* const* d_in, const int* in_sizes, int n_in,
                              void* d_out, int out_size, void* d_ws, size_t ws_size,
                              hipStream_t stream) {
    const float* logits   = (const float*)d_in[0];
    const int*   labels   = (const int*)d_in[1];
    const int*   seq_lens = (const int*)d_in[2];
    const float* trans    = (const float*)d_in[3];
    float* out = (float*)d_out;

    (void)hipMemsetAsync(out, 0, sizeof(float), stream);
    crf_nll_kernel<<<dim3(Bdim), dim3(NT), 0, stream>>>(
        logits, labels, seq_lens, trans, out);
}

// Round 10
// 246.203 us; speedup vs baseline: 1.0889x; 1.0889x over previous
//
#include <hip/hip_runtime.h>

#define Bdim 256
#define Tdim 512
#define Kdim 128
#define NT   256   // thread (j4 = tid>>3, g = tid&7): 4 columns x 16-row slice
#define CHUNK 8

typedef float v2f __attribute__((ext_vector_type(2)));

// Raw barrier: drain LDS ops only (NOT vmcnt) so global prefetches stay in
// flight across steps; then s_barrier. "memory" stops compiler reordering.
#define BAR() asm volatile("s_waitcnt lgkmcnt(0)\n\ts_barrier" ::: "memory")

// DPP butterfly add. 0xB1 = quad_perm [1,0,3,2] (xor 1); 0x4E = [2,3,0,1]
// (xor 2); 0x141 = row_half_mirror (lane i <-> 7-i within each 8-lane half-
// row: after xor1+xor2 it adds the other quad's total -> full 8-lane sum).
template <int CTRL>
__device__ __forceinline__ float dpp_add(float v) {
    int r = __builtin_amdgcn_update_dpp(0, __float_as_int(v), CTRL, 0xF, 0xF, true);
    return v + __int_as_float(r);
}

// ===== ROUND 10: exact round-8 kernel (fastest so far, 171us) with ONE
// change: __launch_bounds__(NT) one-arg + amdgpu_waves_per_eu(1,1).
// r9 showed the 2-arg form launch_bounds(NT,1) CANCELS the waves_per_eu
// attribute (r8: VGPR 60 = E remat'd into the loop; r9 one-arg: VGPR 132).
// This isolates the register-residency lever at the empirically-best wave
// count (4 waves: 810cy/step vs 930 @8w, 920 @2w, 1118 @16w).
// Geometry: thread (j4, g) accumulates columns {4j4..4j4+3} over rows
// [16g, 16g+16): 64-float E fragment as 32 v2f; live set ~110 < 256 cap.
// Per step: 4 ds_read_b128 (bank-staggered), 32 v_pk_fma_f32, 12 DPP adds,
// select, 1 mul, masked ds_write, lgkm-only barrier. alpha in LINEAR space;
// renormalize by A[0] every 4th step (growth <= ~1e16 per 4 steps).
__global__ __launch_bounds__(NT) __attribute__((amdgpu_waves_per_eu(1, 1)))
void crf_nll_kernel(
    const float* __restrict__ logits,   // B*T*K fp32
    const int*   __restrict__ labels,   // B*T   int32
    const int*   __restrict__ seq_lens, // B     int32
    const float* __restrict__ trans,    // K*K   fp32
    float* __restrict__ out)            // 1     fp32 (pre-zeroed)
{
    const int b   = blockIdx.x;
    const int tid = threadIdx.x;
    const int j4  = tid >> 3;           // column set 0..31 (cols 4j4..4j4+3)
    const int g   = tid & 7;            // row-slice group 0..7
    const int cj  = 4 * j4 + (g & 3);   // this lane's write/logit column
    const int L   = seq_lens[b];        // 1..T (uniform per block)

    __shared__ float pbuf[2][Kdim];
    __shared__ float sred[NT / 64];

    const int*   lab_b   = labels + (size_t)b * Tdim;
    const float* logit_b = logits + (size_t)b * Tdim * Kdim;

    // ---- E fragment (16 rows x 4 cols) as v2f pairs. Read-inst ii accesses
    // float4 idx = 4g + ((ii+g)&3): per instruction the 8 distinct addresses
    // alias each bank-quad exactly 2-way (free, m136).
    v2f e01[4][4], e23[4][4];
    #pragma unroll
    for (int ii = 0; ii < 4; ++ii) {
        const int row0 = 16 * g + (((ii + g) & 3) << 2);
        #pragma unroll
        for (int ci = 0; ci < 4; ++ci) {
            const float4 tr =
                *(const float4*)&trans[(size_t)(row0 + ci) * Kdim + 4 * j4];
            e01[ii][ci] = (v2f){__expf(tr.x), __expf(tr.y)};
            e23[ii][ci] = (v2f){__expf(tr.z), __expf(tr.w)};
        }
    }

    // ---- gold-path score: 2 timesteps per thread ----
    float s = 0.f;
    #pragma unroll
    for (int t0 = 0; t0 < Tdim; t0 += NT) {
        const int t = t0 + tid;
        if (t < L) {
            const int lb = lab_b[t];
            s += logit_b[(size_t)t * Kdim + lb];
            if (t >= 1) s += trans[(size_t)lab_b[t - 1] * Kdim + lb];
        }
    }
    #pragma unroll
    for (int o = 32; o > 0; o >>= 1) s += __shfl_down(s, o, 64);
    if ((tid & 63) == 0) sred[tid >> 6] = s;

    // ---- init alpha (t = 0), linear space; g<4 lanes own a column ----
    if (g < 4) pbuf[0][cj] = __expf(logit_b[cj]);
    float off = 0.f;
    int cb = 0;
    __syncthreads();

    float score = 0.f;
    if (tid == 0) {
        #pragma unroll
        for (int w = 0; w < NT / 64; ++w) score += sred[w];
    }

    // ---- prefetch first logit chunk (t = 1..8), this lane's column ----
    float curl[CHUNK], nxtl[CHUNK], ex[CHUNK];
    #pragma unroll
    for (int u = 0; u < CHUNK; ++u) {
        const int tt = 1 + u;
        curl[u] = (tt < Tdim) ? logit_b[(size_t)tt * Kdim + cj] : 0.f;
    }

    // ---- forward recursion ----
    for (int tb = 1; tb < L; tb += CHUNK) {
        #pragma unroll
        for (int u = 0; u < CHUNK; ++u) {    // prefetch next chunk
            const int tt = tb + CHUNK + u;
            nxtl[u] = (tt < Tdim) ? logit_b[(size_t)tt * Kdim + cj] : 0.f;
        }
        #pragma unroll
        for (int u = 0; u < CHUNK; ++u)      // exp(logit) off the serial path
            ex[u] = __expf(curl[u]);
        #pragma unroll
        for (int u = 0; u < CHUNK; ++u) {
            const int t = tb + u;
            if (t < L) {                     // uniform per block
                const float4* a4 = (const float4*)pbuf[cb];
                float p0 = 1.f;
                if ((u & 3) == 3) p0 = pbuf[cb][0];   // renorm steps only
                v2f A0 = {0.f, 0.f}, A1 = {0.f, 0.f};
                v2f B0 = {0.f, 0.f}, B1 = {0.f, 0.f};
                #pragma unroll
                for (int ii = 0; ii < 4; ++ii) {
                    const float4 p = a4[(g << 2) + ((ii + g) & 3)];
                    A0 = __builtin_elementwise_fma((v2f){p.x, p.x}, e01[ii][0], A0);
                    A1 = __builtin_elementwise_fma((v2f){p.x, p.x}, e23[ii][0], A1);
                    B0 = __builtin_elementwise_fma((v2f){p.y, p.y}, e01[ii][1], B0);
                    B1 = __builtin_elementwise_fma((v2f){p.y, p.y}, e23[ii][1], B1);
                    A0 = __builtin_elementwise_fma((v2f){p.z, p.z}, e01[ii][2], A0);
                    A1 = __builtin_elementwise_fma((v2f){p.z, p.z}, e23[ii][2], A1);
                    B0 = __builtin_elementwise_fma((v2f){p.w, p.w}, e01[ii][3], B0);
                    B1 = __builtin_elementwise_fma((v2f){p.w, p.w}, e23[ii][3], B1);
                }
                const v2f s01 = A0 + B0;     // cols (4j4+0, 4j4+1)
                const v2f s23 = A1 + B1;     // cols (4j4+2, 4j4+3)
                float c0 = s01.x, c1 = s01.y, c2 = s23.x, c3 = s23.y;
                // 8-lane reduce per column, pure DPP
                c0 = dpp_add<0xB1>(c0); c0 = dpp_add<0x4E>(c0); c0 = dpp_add<0x141>(c0);
                c1 = dpp_add<0xB1>(c1); c1 = dpp_add<0x4E>(c1); c1 = dpp_add<0x141>(c1);
                c2 = dpp_add<0xB1>(c2); c2 = dpp_add<0x4E>(c2); c2 = dpp_add<0x141>(c2);
                c3 = dpp_add<0xB1>(c3); c3 = dpp_add<0x4E>(c3); c3 = dpp_add<0x141>(c3);
                // select this lane's column (c = g&3)
                float sel  = (g & 1) ? c1 : c0;
                float selh = (g & 1) ? c3 : c2;
                sel = (g & 2) ? selh : sel;
                float anew = sel * ex[u];
                if ((u & 3) == 3) {          // renormalize by A[0]
                    const float lp0 = __logf(p0);
                    anew *= __expf(-lp0);
                    off  += lp0;
                }
                if (g < 4) pbuf[cb ^ 1][cj] = anew;
                cb ^= 1;
                BAR();                       // lgkm-only barrier per step
            }
        }
        #pragma unroll
        for (int u = 0; u < CHUNK; ++u) curl[u] = nxtl[u];
    }

    // ---- log_z = off + log(sum_j A[j]); nll = log_z - score ----
    __syncthreads();
    float as = (tid < Kdim) ? pbuf[cb][tid] : 0.f;
    #pragma unroll
    for (int o = 32; o > 0; o >>= 1) as += __shfl_down(as, o, 64);
    __syncthreads();
    if ((tid & 63) == 0) sred[tid >> 6] = as;
    __syncthreads();
    if (tid == 0) {
        float tot = 0.f;
        #pragma unroll
        for (int w = 0; w < NT / 64; ++w) tot += sred[w];
        const float logz = off + __logf(tot);
        atomicAdd(out, logz - score);
    }
}

extern "C" void kernel_launch(void* const* d_in, const int* in_sizes, int n_in,
                              void* d_out, int out_size, void* d_ws, size_t ws_size,
                              hipStream_t stream) {
    const float* logits   = (const float*)d_in[0];
    const int*   labels   = (const int*)d_in[1];
    const int*   seq_lens = (const int*)d_in[2];
    const float* trans    = (const float*)d_in[3];
    float* out = (float*)d_out;

    (void)hipMemsetAsync(out, 0, sizeof(float), stream);
    crf_nll_kernel<<<dim3(Bdim), dim3(NT), 0, stream>>>(
        logits, labels, seq_lens, trans, out);
}

// Round 11
// 237.187 us; speedup vs baseline: 1.1303x; 1.0380x over previous
//
#include <hip/hip_runtime.h>

#define Bdim 256
#define Tdim 512
#define Kdim 128
#define NT   256   // thread (j4 = tid>>3, g = tid&7): 4 columns x 16-row slice
#define CHUNK 8

typedef float v2f __attribute__((ext_vector_type(2)));

// Raw barrier: drain LDS ops only (NOT vmcnt) so global prefetches stay in
// flight across steps; then s_barrier. "memory" stops compiler reordering.
#define BAR() asm volatile("s_waitcnt lgkmcnt(0)\n\ts_barrier" ::: "memory")

// DPP butterfly add. 0xB1 = quad_perm [1,0,3,2] (xor 1); 0x4E = [2,3,0,1]
// (xor 2); 0x141 = row_half_mirror (lane i <-> 7-i within each 8-lane half-
// row: after xor1+xor2 it adds the other quad's total -> full 8-lane sum).
template <int CTRL>
__device__ __forceinline__ float dpp_add(float v) {
    int r = __builtin_amdgcn_update_dpp(0, __float_as_int(v), CTRL, 0xF, 0xF, true);
    return v + __int_as_float(r);
}

// ===== ROUND 11: r10 (171us dispatch, VGPR 132, E resident) + two fixes:
// (1) TRUE conflict-free read stagger. r10's f = 4g + ((ii+g)&3) covers only
//     4 of 8 bank-quads (f mod 8 = 4(g&1) + ((ii+g)&3) collides for g and
//     g+4) -> every ds_read_b128 was 2-way conflicted = the counted 4.6M
//     cycles (~47cy/step/block) on the read critical path. New rotation
//     r(g) = (ii + (g>>1)) & 3 makes f mod 8 = 4(g&1) + ((ii + g>>1)&3) a
//     BIJECTION over the 8 bank-quads -> zero conflicts.
// (2) Branchless main loop (full chunks + tail, r9-style) removes the
//     per-step t<L compare/branch/exec churn.
// Geometry unchanged (4 waves = measured optimum: 810cy vs 920@2w, 930@8w,
// 1118@16w): thread (j4,g) owns cols {4j4..4j4+3} x rows [16g,16g+16),
// E as 32 v2f (resident; one-arg launch_bounds + waves_per_eu(1,1) — the
// 2-arg form cancels the attribute, r8 vs r10). Per step: 4 ds_read_b128,
// 32 v_pk_fma_f32, 12 DPP adds, select, mul, masked write, lgkm-only BAR.
// alpha in LINEAR space; renorm by A[0] every 4th step.
__global__ __launch_bounds__(NT) __attribute__((amdgpu_waves_per_eu(1, 1)))
void crf_nll_kernel(
    const float* __restrict__ logits,   // B*T*K fp32
    const int*   __restrict__ labels,   // B*T   int32
    const int*   __restrict__ seq_lens, // B     int32
    const float* __restrict__ trans,    // K*K   fp32
    float* __restrict__ out)            // 1     fp32 (pre-zeroed)
{
    const int b   = blockIdx.x;
    const int tid = threadIdx.x;
    const int j4  = tid >> 3;           // column set 0..31 (cols 4j4..4j4+3)
    const int g   = tid & 7;            // row-slice group 0..7
    const int cj  = 4 * j4 + (g & 3);   // this lane's write/logit column
    const int L   = seq_lens[b];        // 1..T (uniform per block)

    __shared__ float pbuf[2][Kdim];
    __shared__ float sred[NT / 64];

    const int*   lab_b   = labels + (size_t)b * Tdim;
    const float* logit_b = logits + (size_t)b * Tdim * Kdim;

    // ---- E fragment (16 rows x 4 cols) as v2f pairs, bijective stagger:
    // read-inst ii accesses float4 idx f = 4g + ((ii + (g>>1)) & 3).
    v2f e01[4][4], e23[4][4];
    #pragma unroll
    for (int ii = 0; ii < 4; ++ii) {
        const int row0 = 16 * g + (((ii + (g >> 1)) & 3) << 2);
        #pragma unroll
        for (int ci = 0; ci < 4; ++ci) {
            const float4 tr =
                *(const float4*)&trans[(size_t)(row0 + ci) * Kdim + 4 * j4];
            e01[ii][ci] = (v2f){__expf(tr.x), __expf(tr.y)};
            e23[ii][ci] = (v2f){__expf(tr.z), __expf(tr.w)};
        }
    }

    // ---- gold-path score: 2 timesteps per thread ----
    float s = 0.f;
    #pragma unroll
    for (int t0 = 0; t0 < Tdim; t0 += NT) {
        const int t = t0 + tid;
        if (t < L) {
            const int lb = lab_b[t];
            s += logit_b[(size_t)t * Kdim + lb];
            if (t >= 1) s += trans[(size_t)lab_b[t - 1] * Kdim + lb];
        }
    }
    #pragma unroll
    for (int o = 32; o > 0; o >>= 1) s += __shfl_down(s, o, 64);
    if ((tid & 63) == 0) sred[tid >> 6] = s;

    // ---- init alpha (t = 0), linear space; g<4 lanes own a column ----
    if (g < 4) pbuf[0][cj] = __expf(logit_b[cj]);
    float off = 0.f;
    int cb = 0;
    __syncthreads();

    float score = 0.f;
    if (tid == 0) {
        #pragma unroll
        for (int w = 0; w < NT / 64; ++w) score += sred[w];
    }

    // ---- prefetch first logit chunk (t = 1..8), this lane's column ----
    float curl[CHUNK], nxtl[CHUNK], ex[CHUNK];
    #pragma unroll
    for (int u = 0; u < CHUNK; ++u) {
        const int tt = 1 + u;
        curl[u] = (tt < Tdim) ? logit_b[(size_t)tt * Kdim + cj] : 0.f;
    }

    // One forward step. RENORM steps divide by A[0] (uniform) and bank the
    // log into off; growth between renorms is far below fp32 max.
#define STEP_BODY(SC_EXPR, RENORM)                                          \
    do {                                                                    \
        const float4* a4 = (const float4*)pbuf[cb];                         \
        float p0 = 1.f;                                                     \
        if (RENORM) p0 = pbuf[cb][0];                                       \
        v2f A0 = {0.f, 0.f}, A1 = {0.f, 0.f};                               \
        v2f B0 = {0.f, 0.f}, B1 = {0.f, 0.f};                               \
        _Pragma("unroll")                                                   \
        for (int ii = 0; ii < 4; ++ii) {                                    \
            const float4 p = a4[(g << 2) + ((ii + (g >> 1)) & 3)];          \
            A0 = __builtin_elementwise_fma((v2f){p.x, p.x}, e01[ii][0], A0);\
            A1 = __builtin_elementwise_fma((v2f){p.x, p.x}, e23[ii][0], A1);\
            B0 = __builtin_elementwise_fma((v2f){p.y, p.y}, e01[ii][1], B0);\
            B1 = __builtin_elementwise_fma((v2f){p.y, p.y}, e23[ii][1], B1);\
            A0 = __builtin_elementwise_fma((v2f){p.z, p.z}, e01[ii][2], A0);\
            A1 = __builtin_elementwise_fma((v2f){p.z, p.z}, e23[ii][2], A1);\
            B0 = __builtin_elementwise_fma((v2f){p.w, p.w}, e01[ii][3], B0);\
            B1 = __builtin_elementwise_fma((v2f){p.w, p.w}, e23[ii][3], B1);\
        }                                                                   \
        const v2f s01 = A0 + B0;   /* cols (4j4+0, 4j4+1) */                \
        const v2f s23 = A1 + B1;   /* cols (4j4+2, 4j4+3) */                \
        float c0 = s01.x, c1 = s01.y, c2 = s23.x, c3 = s23.y;               \
        c0 = dpp_add<0xB1>(c0); c0 = dpp_add<0x4E>(c0); c0 = dpp_add<0x141>(c0);\
        c1 = dpp_add<0xB1>(c1); c1 = dpp_add<0x4E>(c1); c1 = dpp_add<0x141>(c1);\
        c2 = dpp_add<0xB1>(c2); c2 = dpp_add<0x4E>(c2); c2 = dpp_add<0x141>(c2);\
        c3 = dpp_add<0xB1>(c3); c3 = dpp_add<0x4E>(c3); c3 = dpp_add<0x141>(c3);\
        float sel  = (g & 1) ? c1 : c0;                                     \
        float selh = (g & 1) ? c3 : c2;                                     \
        sel = (g & 2) ? selh : sel;                                         \
        float anew = sel * (SC_EXPR);                                       \
        if (RENORM) {                                                       \
            const float lp0 = __logf(p0);                                   \
            anew *= __expf(-lp0);                                           \
            off  += lp0;                                                    \
        }                                                                   \
        if (g < 4) pbuf[cb ^ 1][cj] = anew;                                 \
        cb ^= 1;                                                            \
        BAR();                                                              \
    } while (0)

    // ---- forward recursion: branchless full chunks, then a short tail ----
    int tb = 1;
    for (; tb + CHUNK <= L; tb += CHUNK) {
        #pragma unroll
        for (int u = 0; u < CHUNK; ++u) {    // prefetch next chunk
            const int tt = tb + CHUNK + u;
            nxtl[u] = (tt < Tdim) ? logit_b[(size_t)tt * Kdim + cj] : 0.f;
        }
        #pragma unroll
        for (int u = 0; u < CHUNK; ++u)      // exp(logit) off the serial path
            ex[u] = __expf(curl[u]);
        #pragma unroll
        for (int u = 0; u < CHUNK; ++u)      // no per-step t<L check
            STEP_BODY(ex[u], (u & 3) == 3);
        #pragma unroll
        for (int u = 0; u < CHUNK; ++u) curl[u] = nxtl[u];
    }
    // tail: < CHUNK remaining steps; curl[] already holds t = tb..tb+7
    for (int u = 0; tb + u < L; ++u)
        STEP_BODY(__expf(curl[u]), (u & 3) == 3);

#undef STEP_BODY

    // ---- log_z = off + log(sum_j A[j]); nll = log_z - score ----
    __syncthreads();
    float as = (tid < Kdim) ? pbuf[cb][tid] : 0.f;
    #pragma unroll
    for (int o = 32; o > 0; o >>= 1) as += __shfl_down(as, o, 64);
    __syncthreads();
    if ((tid & 63) == 0) sred[tid >> 6] = as;
    __syncthreads();
    if (tid == 0) {
        float tot = 0.f;
        #pragma unroll
        for (int w = 0; w < NT / 64; ++w) tot += sred[w];
        const float logz = off + __logf(tot);
        atomicAdd(out, logz - score);
    }
}

extern "C" void kernel_launch(void* const* d_in, const int* in_sizes, int n_in,
                              void* d_out, int out_size, void* d_ws, size_t ws_size,
                              hipStream_t stream) {
    const float* logits   = (const float*)d_in[0];
    const int*   labels   = (const int*)d_in[1];
    const int*   seq_lens = (const int*)d_in[2];
    const float* trans    = (const float*)d_in[3];
    float* out = (float*)d_out;

    (void)hipMemsetAsync(out, 0, sizeof(float), stream);
    crf_nll_kernel<<<dim3(Bdim), dim3(NT), 0, stream>>>(
        logits, labels, seq_lens, trans, out);
}